// Round 8
// baseline (456.563 us; speedup 1.0000x reference)
//
#include <hip/hip_runtime.h>
#include <hip/hip_bf16.h>

#define HID 512
#define OD  256
#define HP  513
#define NBLK 1026            /* 131328 rows / 128 per block */
#define EPSV 1e-5f

typedef float f32x4 __attribute__((ext_vector_type(4)));
typedef short s16x8 __attribute__((ext_vector_type(8)));

static __device__ __forceinline__ unsigned short f2bf(float f) {
    union { float f; unsigned u; } x; x.f = f;
    unsigned r = x.u + 0x7FFFu + ((x.u >> 16) & 1u);   // RNE
    return (unsigned short)(r >> 16);
}
static __device__ __forceinline__ unsigned pkbf(float x, float y) {
    float2 t; t.x = x; t.y = y;
    __hip_bfloat162 h = __float22bfloat162_rn(t);
    union { __hip_bfloat162 h; unsigned u; } c; c.h = h;
    return c.u;
}

// permuted k-storage: within a 256-col half, storage s=(ll*8+c) holds true col c*32+ll.
// Applied identically to gpb/bpb/vhT so MFMA contraction pairing stays consistent.

// ---------- prep: gpb/bpb (bf16, permuted), vhT (bf16, permuted), vh512, ahT -
__global__ void prep_all(const float* __restrict__ a, const float* __restrict__ v,
                         const float* __restrict__ gamma, const float* __restrict__ beta,
                         unsigned short* __restrict__ gpb, unsigned short* __restrict__ bpb,
                         unsigned short* __restrict__ vhT, float* __restrict__ vh512,
                         float* __restrict__ ahT) {
    int b = blockIdx.x, t = threadIdx.x;
    if (b < HP) {
        int ii = b;
        for (int s = t; s < 512; s += 256) {
            int half = s >> 8, ss = s & 255, ll = ss >> 3, c = ss & 7;
            int j = half * 256 + c * 32 + ll;
            gpb[(size_t)ii * 512 + s] = f2bf(gamma[(size_t)ii * HP + j]);
            bpb[(size_t)ii * 512 + s] = f2bf(beta [(size_t)ii * HP + j]);
        }
    } else if (b < HP + 128) {
        int m = b - HP;
        for (int s = t; s < 512; s += 256) {
            int half = s >> 8, ss = s & 255, ll = ss >> 3, c = ss & 7;
            int j = half * 256 + c * 32 + ll;
            float val = (j == 0) ? 1.f : v[m * HID + j - 1];
            vhT[(size_t)m * 512 + s] = f2bf(val);
        }
    } else if (b == HP + 128) {
        if (t < 128) vh512[t] = v[t * HID + 511];
    } else {
        int idx = (b - HP - 129) * 256 + t;
        if (idx < HP * 128) {
            int i = idx >> 7, m = idx & 127;
            ahT[idx] = (i == 0) ? 1.f : a[m * HID + i - 1];
        }
    }
}

// ---------- prep2: gather col-512 of W, pre-scaled by gamma/beta -------------
__global__ void prep_w5(const float* __restrict__ W, const float* __restrict__ gamma,
                        const float* __restrict__ beta,
                        float* __restrict__ w5g, float* __restrict__ w5b) {
    int oi = blockIdx.x * 256 + threadIdx.x;
    if (oi < NBLK * 128) {
        unsigned ii = (unsigned)oi % 513u;
        float wv = W[(size_t)oi * 513u + 512u];
        w5g[oi] = gamma[(size_t)ii * HP + 512] * wv;
        w5b[oi] = beta [(size_t)ii * HP + 512] * wv;
    }
}

// ---------- stats ------------------------------------------------------------
__global__ void stats_kernel(const float* __restrict__ a, const float* __restrict__ v,
                             float* __restrict__ mu, float* __restrict__ rsig) {
    __shared__ float s1[256], s2[256], s3[256], s4[256];
    int m = blockIdx.x, t = threadIdx.x;
    float a0 = a[m * HID + t], a1 = a[m * HID + t + 256];
    float v0 = v[m * HID + t], v1 = v[m * HID + t + 256];
    s1[t] = a0 + a1; s2[t] = a0 * a0 + a1 * a1;
    s3[t] = v0 + v1; s4[t] = v0 * v0 + v1 * v1;
    __syncthreads();
    for (int off = 128; off > 0; off >>= 1) {
        if (t < off) { s1[t] += s1[t + off]; s2[t] += s2[t + off];
                       s3[t] += s3[t + off]; s4[t] += s4[t + off]; }
        __syncthreads();
    }
    if (t == 0) {
        float Sa = 1.f + s1[0], Qa = 1.f + s2[0];
        float Sv = 1.f + s3[0], Qv = 1.f + s4[0];
        float muv = Sa * Sv / (float)((float)HP * (float)HP);
        float var = Qa * Qv / (float)((float)HP * (float)HP) - muv * muv;
        mu[m]   = muv;
        rsig[m] = rsqrtf(var + EPSV);
    }
}

// ---------- fused: reg-staged W stream, raw-barrier pipeline -----------------
// 16 bodies = 8 row-groups x 2 col-halves. Per body: prefetch next W(8 dw) +
// gamma(bf16 x8) into ping-pong regs; convert current -> bf16 A-tile (LDS,
// dbuf); lgkmcnt(0)+s_barrier (NO vmcnt drain); 8 MFMA vs reg B-frags;
// ah-fold per group. Col 512 peeled to finalize.
__global__ __launch_bounds__(512, 4) void stage_fused(
        const float* __restrict__ W, const unsigned short* __restrict__ gpb,
        const unsigned short* __restrict__ bpb, const unsigned short* __restrict__ vhT,
        const float* __restrict__ ahT,
        float* __restrict__ Pblk, float* __restrict__ SgPart, float* __restrict__ SbPart) {
    __shared__ __align__(16) char bt[2][16 * 528];
    __shared__ float redS[32];

    const int tid = threadIdx.x, lane = tid & 63, w = tid >> 6;
    const int lr = lane & 15, lg = lane >> 4, ll = lane & 31;
    const int cr = 2 * w + (lane >> 5);      // conv row 0..15 (wave-local)
    const int m  = w * 16 + lr;
    const int b = blockIdx.x, gr0 = b * 128;
    const unsigned lo0 = ((unsigned)gr0 / 513u) * 513u;
    const unsigned osw = lo0 + 513u;

    // B-fragments register-resident (permuted vhT, L2-hot)
    s16x8 bfr[16];
    {
        const unsigned short* vrow = vhT + (size_t)m * 512 + lg * 8;
#pragma unroll
        for (int k = 0; k < 16; ++k) {
            int half = k >> 3, ksl = k & 7;
            bfr[k] = *(const s16x8*)(vrow + half * 256 + ksl * 32);
        }
    }

    float Wr0[8], Wr1[8];
    uint4 ga0, ga1;
    float ahv[4];
    f32x4 acc = {0.f, 0.f, 0.f, 0.f};
    float psum0 = 0.f, psum1 = 0.f, sg0 = 0.f, sg1 = 0.f, sb0 = 0.f, sb1 = 0.f;

    auto iirow = [&](int t) -> unsigned {
        unsigned oi = (unsigned)(gr0 + (t >> 1) * 16 + cr);
        return oi - (oi >= osw ? osw : lo0);
    };
    auto LOADW = [&](int t, float (&dst)[8]) {
        const float* p = W + (size_t)(gr0 + (t >> 1) * 16 + cr) * 513u + (t & 1) * 256 + ll;
#pragma unroll
        for (int c = 0; c < 8; ++c) dst[c] = p[c * 32];
    };
    auto LOADG = [&](int t) -> uint4 {
        return *(const uint4*)(gpb + (size_t)iirow(t) * 512 + (t & 1) * 256 + ll * 8);
    };
    auto CONV = [&](const float (&Wc)[8], const uint4 gc, const uint4 b4,
                    bool hi_c, char* tile) {
        const unsigned gw[4] = {gc.x, gc.y, gc.z, gc.w};
        float p[8], s = 0.f;
#pragma unroll
        for (int e = 0; e < 8; ++e) {
            unsigned u = (e & 1) ? (gw[e >> 1] >> 16) : (gw[e >> 1] & 0xffffu);
            union { unsigned q; float f; } cv; cv.q = u << 16;
            p[e] = cv.f * Wc[e];
            s += p[e];
        }
        uint4 o4;
        o4.x = pkbf(p[0], p[1]); o4.y = pkbf(p[2], p[3]);
        o4.z = pkbf(p[4], p[5]); o4.w = pkbf(p[6], p[7]);
        *(uint4*)(tile + cr * 528 + ll * 16) = o4;
        const unsigned bw[4] = {b4.x, b4.y, b4.z, b4.w};
        float t2 = 0.f;
#pragma unroll
        for (int e = 0; e < 8; ++e) {
            unsigned u = (e & 1) ? (bw[e >> 1] >> 16) : (bw[e >> 1] & 0xffffu);
            union { unsigned q; float f; } cv; cv.q = u << 16;
            t2 = fmaf(cv.f, Wc[e], t2);
        }
        if (hi_c) { sg1 += s; sb1 += t2; } else { sg0 += s; sb0 += t2; }
    };

    // prologue
    LOADW(0, Wr0);
    ga0 = LOADG(0);

#pragma unroll
    for (int t = 0; t < 16; ++t) {
        const int g = t >> 1, half = t & 1;
        const unsigned ii_c = iirow(t);
        const bool hi_c = ((unsigned)(gr0 + g * 16 + cr) >= osw);

        // transient beta(t) — issued first (oldest among this body's loads)
        uint4 b4 = *(const uint4*)(bpb + (size_t)ii_c * 512 + half * 256 + ll * 8);
        // prefetch W(t+1), gamma(t+1) into the alternate set
        if (t < 15) {
            if (half == 0) { LOADW(t + 1, Wr1); ga1 = LOADG(t + 1); }
            else           { LOADW(t + 1, Wr0); ga0 = LOADG(t + 1); }
        }
        // prefetch ah(g) on even bodies (used at odd-body fold)
        if (half == 0) {
#pragma unroll
            for (int e = 0; e < 4; ++e) {
                unsigned oi = (unsigned)(gr0 + g * 16 + lg * 4 + e);
                unsigned ii = oi - (oi >= osw ? osw : lo0);
                ahv[e] = ahT[(size_t)ii * 128 + m];
            }
        }
        // convert current body (waits only its own W/gamma/beta — counted)
        if (half == 0) CONV(Wr0, ga0, b4, hi_c, bt[0]);
        else           CONV(Wr1, ga1, b4, hi_c, bt[1]);

        // raw barrier: flush LDS writes only; vmcnt stays in flight
        __builtin_amdgcn_sched_barrier(0);
        asm volatile("s_waitcnt lgkmcnt(0)" ::: "memory");
        __builtin_amdgcn_s_barrier();
        __builtin_amdgcn_sched_barrier(0);

        // MFMA: 8 k-slices of this half
#pragma unroll
        for (int ksl = 0; ksl < 8; ++ksl) {
            s16x8 afr = *(const s16x8*)(&bt[half][lr * 528 + ksl * 64 + lg * 16]);
            acc = __builtin_amdgcn_mfma_f32_16x16x32_bf16(afr, bfr[half * 8 + ksl], acc, 0, 0, 0);
        }
        // group fold on odd bodies
        if (half == 1) {
#pragma unroll
            for (int e = 0; e < 4; ++e) {
                unsigned oi = (unsigned)(gr0 + g * 16 + lg * 4 + e);
                float val = acc[e] * ahv[e];
                if (oi >= osw) psum1 += val; else psum0 += val;
            }
            acc = (f32x4){0.f, 0.f, 0.f, 0.f};
        }
    }

    // ---- epilogue ------------------------------------------------------------
    psum0 += __shfl_xor(psum0, 16); psum0 += __shfl_xor(psum0, 32);
    psum1 += __shfl_xor(psum1, 16); psum1 += __shfl_xor(psum1, 32);
    if (lane < 16) {
        Pblk[((size_t)b * 2 + 0) * 128 + m] = psum0;
        Pblk[((size_t)b * 2 + 1) * 128 + m] = psum1;
    }
#pragma unroll
    for (int off = 1; off < 64; off <<= 1) {
        sg0 += __shfl_xor(sg0, off); sg1 += __shfl_xor(sg1, off);
        sb0 += __shfl_xor(sb0, off); sb1 += __shfl_xor(sb1, off);
    }
    if (lane == 0) { redS[w] = sg0; redS[8 + w] = sg1; redS[16 + w] = sb0; redS[24 + w] = sb1; }
    __syncthreads();
    if (tid < 2) {
        float S = 0.f, T = 0.f;
#pragma unroll
        for (int k = 0; k < 8; ++k) { S += redS[tid * 8 + k]; T += redS[16 + tid * 8 + k]; }
        SgPart[b * 2 + tid] = S;
        SbPart[b * 2 + tid] = T;
    }
}

// ---------- finalize: col-512 peel + LN fold + bias + relu -------------------
__global__ void finalize_kernel(const float* __restrict__ Pblk, const float* __restrict__ SgPart,
                                const float* __restrict__ SbPart, const float* __restrict__ w5g,
                                const float* __restrict__ w5b, const float* __restrict__ ahT,
                                const float* __restrict__ vh512, const float* __restrict__ mu,
                                const float* __restrict__ rsig, const float* __restrict__ bias,
                                float* __restrict__ out) {
    __shared__ float wg[HP], wb[HP];
    int o = blockIdx.x, m = threadIdx.x;   // 128 threads
    for (int i = m; i < HP; i += 128) {
        wg[i] = w5g[(size_t)o * HP + i];
        wb[i] = w5b[(size_t)o * HP + i];
    }
    __syncthreads();
    float Pf = 0.f, Sgf = 0.f, Sbf = 0.f;
    for (int i = 0; i < HP; ++i) {
        float g = wg[i];
        Pf = fmaf(ahT[(size_t)i * 128 + m], g, Pf);
        Sgf += g; Sbf += wb[i];
    }
    int b0 = (o * HP) >> 7, b1 = (o * HP + 512) >> 7;
    float P = 0.f, Sg = 0.f, Sb = 0.f;
    for (int bb = b0; bb <= b1; ++bb) {
        unsigned of = ((unsigned)bb * 128u) / 513u;
        int sl = o - (int)of;
        if (sl < 0 || sl > 1) continue;
        P  += Pblk[((size_t)bb * 2 + sl) * 128 + m];
        Sg += SgPart[bb * 2 + sl];
        Sb += SbPart[bb * 2 + sl];
    }
    P += vh512[m] * Pf;
    Sg += Sgf;
    Sb += Sbf;
    float x = rsig[m] * (P - mu[m] * Sg) + Sb + bias[o];
    out[m * OD + o] = fmaxf(x, 0.f);
}

extern "C" void kernel_launch(void* const* d_in, const int* in_sizes, int n_in,
                              void* d_out, int out_size, void* d_ws, size_t ws_size,
                              hipStream_t stream) {
    const float* a     = (const float*)d_in[0];
    const float* v     = (const float*)d_in[1];
    const float* gamma = (const float*)d_in[2];
    const float* beta  = (const float*)d_in[3];
    const float* W     = (const float*)d_in[4];
    const float* bias  = (const float*)d_in[5];
    float* out = (float*)d_out;

    float* cur = (float*)d_ws;
    float* mu     = cur; cur += 128;
    float* rsig   = cur; cur += 128;
    float* SgPart = cur; cur += NBLK * 2;               // 2052
    float* SbPart = cur; cur += NBLK * 2;               // 2052
    float* Pblk   = cur; cur += (size_t)NBLK * 2 * 128; // 262656
    float* ahT    = cur; cur += (size_t)HP * 128;       // 65664
    float* vh512  = cur; cur += 128;
    float* w5g    = cur; cur += (size_t)NBLK * 128;     // 131328
    float* w5b    = cur; cur += (size_t)NBLK * 128;     // 131328
    unsigned short* gpb = (unsigned short*)cur;          // 513*512
    unsigned short* bpb = gpb + (size_t)HP * 512;
    unsigned short* vhT = bpb + (size_t)HP * 512;        // 128*512

    prep_all<<<HP + 128 + 1 + 257, 256, 0, stream>>>(a, v, gamma, beta, gpb, bpb, vhT, vh512, ahT);
    prep_w5<<<HP, 256, 0, stream>>>(W, gamma, beta, w5g, w5b);
    stats_kernel<<<128, 256, 0, stream>>>(a, v, mu, rsig);
    stage_fused<<<NBLK, 512, 0, stream>>>(W, gpb, bpb, vhT, ahT, Pblk, SgPart, SbPart);
    finalize_kernel<<<OD, 128, 0, stream>>>(Pblk, SgPart, SbPart, w5g, w5b, ahT, vh512,
                                            mu, rsig, bias, out);
}

// Round 9
// 274.275 us; speedup vs baseline: 1.6646x; 1.6646x over previous
//
#include <hip/hip_runtime.h>
#include <hip/hip_bf16.h>

#define HID 512
#define OD  256
#define HP  513
#define NBLK 1026            /* 131328 rows / 128 per block */
#define EPSV 1e-5f

typedef float f32x4 __attribute__((ext_vector_type(4)));
typedef short s16x8 __attribute__((ext_vector_type(8)));

static __device__ __forceinline__ unsigned short f2bf(float f) {
    union { float f; unsigned u; } x; x.f = f;
    unsigned r = x.u + 0x7FFFu + ((x.u >> 16) & 1u);   // RNE
    return (unsigned short)(r >> 16);
}
static __device__ __forceinline__ unsigned pkbf(float x, float y) {
    float2 t; t.x = x; t.y = y;
    __hip_bfloat162 h = __float22bfloat162_rn(t);
    union { __hip_bfloat162 h; unsigned u; } c; c.h = h;
    return c.u;
}

// permuted k-storage: within a 256-col half, storage s=(ll*8+c) holds true col c*32+ll.
// Applied identically to gpb/bpb/vhT so MFMA contraction pairing stays consistent.

// ---------- prep: gpb/bpb (bf16, permuted), vhT (bf16, permuted), vh512, ahT -
__global__ void prep_all(const float* __restrict__ a, const float* __restrict__ v,
                         const float* __restrict__ gamma, const float* __restrict__ beta,
                         unsigned short* __restrict__ gpb, unsigned short* __restrict__ bpb,
                         unsigned short* __restrict__ vhT, float* __restrict__ vh512,
                         float* __restrict__ ahT) {
    int b = blockIdx.x, t = threadIdx.x;
    if (b < HP) {
        int ii = b;
        for (int s = t; s < 512; s += 256) {
            int half = s >> 8, ss = s & 255, ll = ss >> 3, c = ss & 7;
            int j = half * 256 + c * 32 + ll;
            gpb[(size_t)ii * 512 + s] = f2bf(gamma[(size_t)ii * HP + j]);
            bpb[(size_t)ii * 512 + s] = f2bf(beta [(size_t)ii * HP + j]);
        }
    } else if (b < HP + 128) {
        int m = b - HP;
        for (int s = t; s < 512; s += 256) {
            int half = s >> 8, ss = s & 255, ll = ss >> 3, c = ss & 7;
            int j = half * 256 + c * 32 + ll;
            float val = (j == 0) ? 1.f : v[m * HID + j - 1];
            vhT[(size_t)m * 512 + s] = f2bf(val);
        }
    } else if (b == HP + 128) {
        if (t < 128) vh512[t] = v[t * HID + 511];
    } else {
        int idx = (b - HP - 129) * 256 + t;
        if (idx < HP * 128) {
            int i = idx >> 7, m = idx & 127;
            ahT[idx] = (i == 0) ? 1.f : a[m * HID + i - 1];
        }
    }
}

// ---------- prep2: gather col-512 of W, pre-scaled by gamma/beta -------------
__global__ void prep_w5(const float* __restrict__ W, const float* __restrict__ gamma,
                        const float* __restrict__ beta,
                        float* __restrict__ w5g, float* __restrict__ w5b) {
    int oi = blockIdx.x * 256 + threadIdx.x;
    if (oi < NBLK * 128) {
        unsigned ii = (unsigned)oi % 513u;
        float wv = W[(size_t)oi * 513u + 512u];
        w5g[oi] = gamma[(size_t)ii * HP + 512] * wv;
        w5b[oi] = beta [(size_t)ii * HP + 512] * wv;
    }
}

// ---------- stats ------------------------------------------------------------
__global__ void stats_kernel(const float* __restrict__ a, const float* __restrict__ v,
                             float* __restrict__ mu, float* __restrict__ rsig) {
    __shared__ float s1[256], s2[256], s3[256], s4[256];
    int m = blockIdx.x, t = threadIdx.x;
    float a0 = a[m * HID + t], a1 = a[m * HID + t + 256];
    float v0 = v[m * HID + t], v1 = v[m * HID + t + 256];
    s1[t] = a0 + a1; s2[t] = a0 * a0 + a1 * a1;
    s3[t] = v0 + v1; s4[t] = v0 * v0 + v1 * v1;
    __syncthreads();
    for (int off = 128; off > 0; off >>= 1) {
        if (t < off) { s1[t] += s1[t + off]; s2[t] += s2[t + off];
                       s3[t] += s3[t + off]; s4[t] += s4[t + off]; }
        __syncthreads();
    }
    if (t == 0) {
        float Sa = 1.f + s1[0], Qa = 1.f + s2[0];
        float Sv = 1.f + s3[0], Qv = 1.f + s4[0];
        float muv = Sa * Sv / (float)((float)HP * (float)HP);
        float var = Qa * Qv / (float)((float)HP * (float)HP) - muv * muv;
        mu[m]   = muv;
        rsig[m] = rsqrtf(var + EPSV);
    }
}

// ---------- fused: reg-staged W stream, raw-barrier pipeline, 3-deep ---------
// 16 bodies = 8 row-groups x 2 col-halves. Per body: issue this-body beta,
// then prefetch W/gamma for body t+2 (3-deep); convert current -> bf16 A-tile
// (LDS dbuf); lgkmcnt(0)+s_barrier (NO vmcnt drain); 8 MFMA vs reg B-frags;
// ah-fold per group. Col 512 peeled to finalize. No launch_bounds cap: ~140
// VGPR, zero spill (WRITE_SIZE is the tripwire).
__global__ __launch_bounds__(512) void stage_fused(
        const float* __restrict__ W, const unsigned short* __restrict__ gpb,
        const unsigned short* __restrict__ bpb, const unsigned short* __restrict__ vhT,
        const float* __restrict__ ahT,
        float* __restrict__ Pblk, float* __restrict__ SgPart, float* __restrict__ SbPart) {
    __shared__ __align__(16) char bt[2][16 * 528];
    __shared__ float redS[32];

    const int tid = threadIdx.x, lane = tid & 63, w = tid >> 6;
    const int lr = lane & 15, lg = lane >> 4, ll = lane & 31;
    const int cr = 2 * w + (lane >> 5);      // conv row 0..15 (wave-local)
    const int m  = w * 16 + lr;
    const int b = blockIdx.x, gr0 = b * 128;
    const unsigned lo0 = ((unsigned)gr0 / 513u) * 513u;
    const unsigned osw = lo0 + 513u;

    // B-fragments register-resident (permuted vhT, L2-hot)
    s16x8 bfr[16];
    {
        const unsigned short* vrow = vhT + (size_t)m * 512 + lg * 8;
#pragma unroll
        for (int k = 0; k < 16; ++k) {
            int half = k >> 3, ksl = k & 7;
            bfr[k] = *(const s16x8*)(vrow + half * 256 + ksl * 32);
        }
    }

    float Wr[3][8];
    uint4 ga[3];
    float ahv[4];
    f32x4 acc = {0.f, 0.f, 0.f, 0.f};
    float psum0 = 0.f, psum1 = 0.f, sg0 = 0.f, sg1 = 0.f, sb0 = 0.f, sb1 = 0.f;

    auto iirow = [&](int t) -> unsigned {
        unsigned oi = (unsigned)(gr0 + (t >> 1) * 16 + cr);
        return oi - (oi >= osw ? osw : lo0);
    };
    auto LOADW = [&](int t, float (&dst)[8]) {
        const float* p = W + (size_t)(gr0 + (t >> 1) * 16 + cr) * 513u + (t & 1) * 256 + ll;
#pragma unroll
        for (int c = 0; c < 8; ++c) dst[c] = p[c * 32];
    };
    auto LOADG = [&](int t) -> uint4 {
        return *(const uint4*)(gpb + (size_t)iirow(t) * 512 + (t & 1) * 256 + ll * 8);
    };
    auto CONV = [&](const float (&Wc)[8], const uint4 gc, const uint4 b4,
                    bool hi_c, char* tile) {
        const unsigned gw[4] = {gc.x, gc.y, gc.z, gc.w};
        float p[8], s = 0.f;
#pragma unroll
        for (int e = 0; e < 8; ++e) {
            unsigned u = (e & 1) ? (gw[e >> 1] >> 16) : (gw[e >> 1] & 0xffffu);
            union { unsigned q; float f; } cv; cv.q = u << 16;
            p[e] = cv.f * Wc[e];
            s += p[e];
        }
        uint4 o4;
        o4.x = pkbf(p[0], p[1]); o4.y = pkbf(p[2], p[3]);
        o4.z = pkbf(p[4], p[5]); o4.w = pkbf(p[6], p[7]);
        *(uint4*)(tile + cr * 528 + ll * 16) = o4;
        const unsigned bw[4] = {b4.x, b4.y, b4.z, b4.w};
        float t2 = 0.f;
#pragma unroll
        for (int e = 0; e < 8; ++e) {
            unsigned u = (e & 1) ? (bw[e >> 1] >> 16) : (bw[e >> 1] & 0xffffu);
            union { unsigned q; float f; } cv; cv.q = u << 16;
            t2 = fmaf(cv.f, Wc[e], t2);
        }
        if (hi_c) { sg1 += s; sb1 += t2; } else { sg0 += s; sb0 += t2; }
    };

    // prologue: 3-deep — issue bodies 0 and 1
    LOADW(0, Wr[0]); ga[0] = LOADG(0);
    LOADW(1, Wr[1]); ga[1] = LOADG(1);

#pragma unroll
    for (int t = 0; t < 16; ++t) {
        const int g = t >> 1, half = t & 1;
        const unsigned ii_c = iirow(t);
        const bool hi_c = ((unsigned)(gr0 + g * 16 + cr) >= osw);

        // transient beta(t) — issued FIRST so its counted wait leaves the
        // later prefetches in flight
        uint4 b4 = *(const uint4*)(bpb + (size_t)ii_c * 512 + half * 256 + ll * 8);
        // prefetch W(t+2), gamma(t+2) into the rotating set (3-deep)
        if (t < 14) {
            LOADW(t + 2, Wr[(t + 2) % 3]);
            ga[(t + 2) % 3] = LOADG(t + 2);
        }
        // prefetch ah(g) on even bodies (used at odd-body fold)
        if (half == 0) {
#pragma unroll
            for (int e = 0; e < 4; ++e) {
                unsigned oi = (unsigned)(gr0 + g * 16 + lg * 4 + e);
                unsigned ii = oi - (oi >= osw ? osw : lo0);
                ahv[e] = ahT[(size_t)ii * 128 + m];
            }
        }
        // convert current body (waits only its own W/gamma/beta — counted)
        CONV(Wr[t % 3], ga[t % 3], b4, hi_c, bt[half]);

        // raw barrier: flush LDS writes only; vmcnt stays in flight
        __builtin_amdgcn_sched_barrier(0);
        asm volatile("s_waitcnt lgkmcnt(0)" ::: "memory");
        __builtin_amdgcn_s_barrier();
        __builtin_amdgcn_sched_barrier(0);

        // MFMA: 8 k-slices of this half
#pragma unroll
        for (int ksl = 0; ksl < 8; ++ksl) {
            s16x8 afr = *(const s16x8*)(&bt[half][lr * 528 + ksl * 64 + lg * 16]);
            acc = __builtin_amdgcn_mfma_f32_16x16x32_bf16(afr, bfr[half * 8 + ksl], acc, 0, 0, 0);
        }
        // group fold on odd bodies
        if (half == 1) {
#pragma unroll
            for (int e = 0; e < 4; ++e) {
                unsigned oi = (unsigned)(gr0 + g * 16 + lg * 4 + e);
                float val = acc[e] * ahv[e];
                if (oi >= osw) psum1 += val; else psum0 += val;
            }
            acc = (f32x4){0.f, 0.f, 0.f, 0.f};
        }
    }

    // ---- epilogue ------------------------------------------------------------
    psum0 += __shfl_xor(psum0, 16); psum0 += __shfl_xor(psum0, 32);
    psum1 += __shfl_xor(psum1, 16); psum1 += __shfl_xor(psum1, 32);
    if (lane < 16) {
        Pblk[((size_t)b * 2 + 0) * 128 + m] = psum0;
        Pblk[((size_t)b * 2 + 1) * 128 + m] = psum1;
    }
#pragma unroll
    for (int off = 1; off < 64; off <<= 1) {
        sg0 += __shfl_xor(sg0, off); sg1 += __shfl_xor(sg1, off);
        sb0 += __shfl_xor(sb0, off); sb1 += __shfl_xor(sb1, off);
    }
    if (lane == 0) { redS[w] = sg0; redS[8 + w] = sg1; redS[16 + w] = sb0; redS[24 + w] = sb1; }
    __syncthreads();
    if (tid < 2) {
        float S = 0.f, T = 0.f;
#pragma unroll
        for (int k = 0; k < 8; ++k) { S += redS[tid * 8 + k]; T += redS[16 + tid * 8 + k]; }
        SgPart[b * 2 + tid] = S;
        SbPart[b * 2 + tid] = T;
    }
}

// ---------- finalize: col-512 peel + LN fold + bias + relu -------------------
__global__ void finalize_kernel(const float* __restrict__ Pblk, const float* __restrict__ SgPart,
                                const float* __restrict__ SbPart, const float* __restrict__ w5g,
                                const float* __restrict__ w5b, const float* __restrict__ ahT,
                                const float* __restrict__ vh512, const float* __restrict__ mu,
                                const float* __restrict__ rsig, const float* __restrict__ bias,
                                float* __restrict__ out) {
    __shared__ float wg[HP], wb[HP];
    int o = blockIdx.x, m = threadIdx.x;   // 128 threads
    for (int i = m; i < HP; i += 128) {
        wg[i] = w5g[(size_t)o * HP + i];
        wb[i] = w5b[(size_t)o * HP + i];
    }
    __syncthreads();
    float Pf = 0.f, Sgf = 0.f, Sbf = 0.f;
    for (int i = 0; i < HP; ++i) {
        float g = wg[i];
        Pf = fmaf(ahT[(size_t)i * 128 + m], g, Pf);
        Sgf += g; Sbf += wb[i];
    }
    int b0 = (o * HP) >> 7, b1 = (o * HP + 512) >> 7;
    float P = 0.f, Sg = 0.f, Sb = 0.f;
    for (int bb = b0; bb <= b1; ++bb) {
        unsigned of = ((unsigned)bb * 128u) / 513u;
        int sl = o - (int)of;
        if (sl < 0 || sl > 1) continue;
        P  += Pblk[((size_t)bb * 2 + sl) * 128 + m];
        Sg += SgPart[bb * 2 + sl];
        Sb += SbPart[bb * 2 + sl];
    }
    P += vh512[m] * Pf;
    Sg += Sgf;
    Sb += Sbf;
    float x = rsig[m] * (P - mu[m] * Sg) + Sb + bias[o];
    out[m * OD + o] = fmaxf(x, 0.f);
}

extern "C" void kernel_launch(void* const* d_in, const int* in_sizes, int n_in,
                              void* d_out, int out_size, void* d_ws, size_t ws_size,
                              hipStream_t stream) {
    const float* a     = (const float*)d_in[0];
    const float* v     = (const float*)d_in[1];
    const float* gamma = (const float*)d_in[2];
    const float* beta  = (const float*)d_in[3];
    const float* W     = (const float*)d_in[4];
    const float* bias  = (const float*)d_in[5];
    float* out = (float*)d_out;

    float* cur = (float*)d_ws;
    float* mu     = cur; cur += 128;
    float* rsig   = cur; cur += 128;
    float* SgPart = cur; cur += NBLK * 2;               // 2052
    float* SbPart = cur; cur += NBLK * 2;               // 2052
    float* Pblk   = cur; cur += (size_t)NBLK * 2 * 128; // 262656
    float* ahT    = cur; cur += (size_t)HP * 128;       // 65664
    float* vh512  = cur; cur += 128;
    float* w5g    = cur; cur += (size_t)NBLK * 128;     // 131328
    float* w5b    = cur; cur += (size_t)NBLK * 128;     // 131328
    unsigned short* gpb = (unsigned short*)cur;          // 513*512
    unsigned short* bpb = gpb + (size_t)HP * 512;
    unsigned short* vhT = bpb + (size_t)HP * 512;        // 128*512

    prep_all<<<HP + 128 + 1 + 257, 256, 0, stream>>>(a, v, gamma, beta, gpb, bpb, vhT, vh512, ahT);
    prep_w5<<<HP, 256, 0, stream>>>(W, gamma, beta, w5g, w5b);
    stats_kernel<<<128, 256, 0, stream>>>(a, v, mu, rsig);
    stage_fused<<<NBLK, 512, 0, stream>>>(W, gpb, bpb, vhT, ahT, Pblk, SgPart, SbPart);
    finalize_kernel<<<OD, 128, 0, stream>>>(Pblk, SgPart, SbPart, w5g, w5b, ahT, vh512,
                                            mu, rsig, bias, out);
}

// Round 10
// 251.666 us; speedup vs baseline: 1.8142x; 1.0898x over previous
//
#include <hip/hip_runtime.h>
#include <hip/hip_bf16.h>

#define HID 512
#define OD  256
#define HP  513
#define NBLK 1026            /* 131328 rows / 128 per block */
#define EPSV 1e-5f

typedef float f32x4 __attribute__((ext_vector_type(4)));
typedef short s16x8 __attribute__((ext_vector_type(8)));

static __device__ __forceinline__ unsigned short f2bf(float f) {
    union { float f; unsigned u; } x; x.f = f;
    unsigned r = x.u + 0x7FFFu + ((x.u >> 16) & 1u);   // RNE
    return (unsigned short)(r >> 16);
}
static __device__ __forceinline__ unsigned pkbf(float x, float y) {
    float2 t; t.x = x; t.y = y;
    __hip_bfloat162 h = __float22bfloat162_rn(t);
    union { __hip_bfloat162 h; unsigned u; } c; c.h = h;
    return c.u;
}

// permuted k-storage: within a 256-col half, storage s=(ll*8+c) holds true col c*32+ll.
// Applied identically to gpb/bpb/vhT so MFMA contraction pairing stays consistent.

// ---------- prep: gpb/bpb (bf16, permuted), vhT (bf16, permuted), vh512, ahT -
__global__ void prep_all(const float* __restrict__ a, const float* __restrict__ v,
                         const float* __restrict__ gamma, const float* __restrict__ beta,
                         unsigned short* __restrict__ gpb, unsigned short* __restrict__ bpb,
                         unsigned short* __restrict__ vhT, float* __restrict__ vh512,
                         float* __restrict__ ahT) {
    int b = blockIdx.x, t = threadIdx.x;
    if (b < HP) {
        int ii = b;
        for (int s = t; s < 512; s += 256) {
            int half = s >> 8, ss = s & 255, ll = ss >> 3, c = ss & 7;
            int j = half * 256 + c * 32 + ll;
            gpb[(size_t)ii * 512 + s] = f2bf(gamma[(size_t)ii * HP + j]);
            bpb[(size_t)ii * 512 + s] = f2bf(beta [(size_t)ii * HP + j]);
        }
    } else if (b < HP + 128) {
        int m = b - HP;
        for (int s = t; s < 512; s += 256) {
            int half = s >> 8, ss = s & 255, ll = ss >> 3, c = ss & 7;
            int j = half * 256 + c * 32 + ll;
            float val = (j == 0) ? 1.f : v[m * HID + j - 1];
            vhT[(size_t)m * 512 + s] = f2bf(val);
        }
    } else if (b == HP + 128) {
        if (t < 128) vh512[t] = v[t * HID + 511];
    } else {
        int idx = (b - HP - 129) * 256 + t;
        if (idx < HP * 128) {
            int i = idx >> 7, m = idx & 127;
            ahT[idx] = (i == 0) ? 1.f : a[m * HID + i - 1];
        }
    }
}

// ---------- prep2: gather col-512 of W, pre-scaled by gamma/beta -------------
__global__ void prep_w5(const float* __restrict__ W, const float* __restrict__ gamma,
                        const float* __restrict__ beta,
                        float* __restrict__ w5g, float* __restrict__ w5b) {
    int oi = blockIdx.x * 256 + threadIdx.x;
    if (oi < NBLK * 128) {
        unsigned ii = (unsigned)oi % 513u;
        float wv = W[(size_t)oi * 513u + 512u];
        w5g[oi] = gamma[(size_t)ii * HP + 512] * wv;
        w5b[oi] = beta [(size_t)ii * HP + 512] * wv;
    }
}

// ---------- stats ------------------------------------------------------------
__global__ void stats_kernel(const float* __restrict__ a, const float* __restrict__ v,
                             float* __restrict__ mu, float* __restrict__ rsig) {
    __shared__ float s1[256], s2[256], s3[256], s4[256];
    int m = blockIdx.x, t = threadIdx.x;
    float a0 = a[m * HID + t], a1 = a[m * HID + t + 256];
    float v0 = v[m * HID + t], v1 = v[m * HID + t + 256];
    s1[t] = a0 + a1; s2[t] = a0 * a0 + a1 * a1;
    s3[t] = v0 + v1; s4[t] = v0 * v0 + v1 * v1;
    __syncthreads();
    for (int off = 128; off > 0; off >>= 1) {
        if (t < off) { s1[t] += s1[t + off]; s2[t] += s2[t + off];
                       s3[t] += s3[t + off]; s4[t] += s4[t + off]; }
        __syncthreads();
    }
    if (t == 0) {
        float Sa = 1.f + s1[0], Qa = 1.f + s2[0];
        float Sv = 1.f + s3[0], Qv = 1.f + s4[0];
        float muv = Sa * Sv / (float)((float)HP * (float)HP);
        float var = Qa * Qv / (float)((float)HP * (float)HP) - muv * muv;
        mu[m]   = muv;
        rsig[m] = rsqrtf(var + EPSV);
    }
}

// ---------- fused: reg-staged W stream, raw-barrier pipeline, B in LDS -------
// B (permuted vhT, 128x512 bf16 = 128 KB) staged to LDS once per block,
// XOR-swizzled so B-frag reads are ~2-way. 16 bodies = 8 row-groups x 2
// halves; per body: this-body beta load, W/gamma prefetch for t+2 (3-deep,
// compiler-counted waits), convert -> bf16 A-tile (LDS dbuf), lgkmcnt(0)+
// s_barrier (vmcnt stays in flight), 8 MFMA (A,B from LDS), ah-fold/group.
__global__ __launch_bounds__(512) void stage_fused(
        const float* __restrict__ W, const unsigned short* __restrict__ gpb,
        const unsigned short* __restrict__ bpb, const unsigned short* __restrict__ vhT,
        const float* __restrict__ ahT,
        float* __restrict__ Pblk, float* __restrict__ SgPart, float* __restrict__ SbPart) {
    __shared__ __align__(16) char Bs[131072];       // [128][1024B], swizzled
    __shared__ __align__(16) char bt[2][16 * 528];  // A-tile dbuf
    __shared__ float redS[32];

    const int tid = threadIdx.x, lane = tid & 63, w = tid >> 6;
    const int lr = lane & 15, lg = lane >> 4, ll = lane & 31;
    const int cr = 2 * w + (lane >> 5);      // conv row 0..15 (wave-local)
    const int m  = w * 16 + lr;
    const int b = blockIdx.x, gr0 = b * 128;
    const unsigned lo0 = ((unsigned)gr0 / 513u) * 513u;
    const unsigned osw = lo0 + 513u;

    // ---- fill B into LDS (swizzled), once per block -------------------------
#pragma unroll
    for (int q = 0; q < 16; ++q) {
        int idx = tid + q * 512;            // 0..8191 16B-chunks
        int mr = idx >> 6, c = idx & 63;
        uint4 val = *(const uint4*)(vhT + (size_t)mr * 512 + c * 8);
        *(uint4*)(&Bs[mr * 1024 + ((c * 16) ^ ((mr & 7) << 4))]) = val;
    }

    float Wr[3][8];
    uint4 ga[3];
    float ahv[4];
    f32x4 acc = {0.f, 0.f, 0.f, 0.f};
    float psum0 = 0.f, psum1 = 0.f, sg0 = 0.f, sg1 = 0.f, sb0 = 0.f, sb1 = 0.f;

    auto iirow = [&](int t) -> unsigned {
        unsigned oi = (unsigned)(gr0 + (t >> 1) * 16 + cr);
        return oi - (oi >= osw ? osw : lo0);
    };
    auto LOADW = [&](int t, float (&dst)[8]) {
        const float* p = W + (size_t)(gr0 + (t >> 1) * 16 + cr) * 513u + (t & 1) * 256 + ll;
#pragma unroll
        for (int c = 0; c < 8; ++c) dst[c] = p[c * 32];
    };
    auto LOADG = [&](int t) -> uint4 {
        return *(const uint4*)(gpb + (size_t)iirow(t) * 512 + (t & 1) * 256 + ll * 8);
    };
    auto CONV = [&](const float (&Wc)[8], const uint4 gc, const uint4 b4,
                    bool hi_c, char* tile) {
        const unsigned gw[4] = {gc.x, gc.y, gc.z, gc.w};
        float p[8], s = 0.f;
#pragma unroll
        for (int e = 0; e < 8; ++e) {
            unsigned u = (e & 1) ? (gw[e >> 1] >> 16) : (gw[e >> 1] & 0xffffu);
            union { unsigned q; float f; } cv; cv.q = u << 16;
            p[e] = cv.f * Wc[e];
            s += p[e];
        }
        uint4 o4;
        o4.x = pkbf(p[0], p[1]); o4.y = pkbf(p[2], p[3]);
        o4.z = pkbf(p[4], p[5]); o4.w = pkbf(p[6], p[7]);
        *(uint4*)(tile + cr * 528 + ll * 16) = o4;
        const unsigned bw[4] = {b4.x, b4.y, b4.z, b4.w};
        float t2 = 0.f;
#pragma unroll
        for (int e = 0; e < 8; ++e) {
            unsigned u = (e & 1) ? (bw[e >> 1] >> 16) : (bw[e >> 1] & 0xffffu);
            union { unsigned q; float f; } cv; cv.q = u << 16;
            t2 = fmaf(cv.f, Wc[e], t2);
        }
        if (hi_c) { sg1 += s; sb1 += t2; } else { sg0 += s; sb0 += t2; }
    };

    // prologue: 3-deep — issue bodies 0 and 1
    LOADW(0, Wr[0]); ga[0] = LOADG(0);
    LOADW(1, Wr[1]); ga[1] = LOADG(1);
    __syncthreads();   // B-fill visible (one-time vmcnt drain is acceptable)

#pragma unroll
    for (int t = 0; t < 16; ++t) {
        const int g = t >> 1, half = t & 1;
        const unsigned ii_c = iirow(t);
        const bool hi_c = ((unsigned)(gr0 + g * 16 + cr) >= osw);

        // transient beta(t) — issued FIRST so CONV's counted wait leaves the
        // t+2 prefetches in flight
        uint4 b4 = *(const uint4*)(bpb + (size_t)ii_c * 512 + half * 256 + ll * 8);
        // prefetch W(t+2), gamma(t+2) into the rotating set (3-deep)
        if (t < 14) {
            LOADW(t + 2, Wr[(t + 2) % 3]);
            ga[(t + 2) % 3] = LOADG(t + 2);
        }
        // prefetch ah(g) on even bodies (used at odd-body fold)
        if (half == 0) {
#pragma unroll
            for (int e = 0; e < 4; ++e) {
                unsigned oi = (unsigned)(gr0 + g * 16 + lg * 4 + e);
                unsigned ii = oi - (oi >= osw ? osw : lo0);
                ahv[e] = ahT[(size_t)ii * 128 + m];
            }
        }
        // convert current body (waits only its own W/gamma/beta — counted)
        CONV(Wr[t % 3], ga[t % 3], b4, hi_c, bt[half]);

        // raw barrier: flush LDS writes only; vmcnt stays in flight
        __builtin_amdgcn_sched_barrier(0);
        asm volatile("s_waitcnt lgkmcnt(0)" ::: "memory");
        __builtin_amdgcn_s_barrier();
        __builtin_amdgcn_sched_barrier(0);

        // MFMA: 8 k-slices of this half; A from bt, B from swizzled Bs
#pragma unroll
        for (int ksl = 0; ksl < 8; ++ksl) {
            s16x8 afr = *(const s16x8*)(&bt[half][lr * 528 + ksl * 64 + lg * 16]);
            s16x8 bfrag = *(const s16x8*)(&Bs[m * 1024 +
                            (((half * 512) + ksl * 64 + lg * 16) ^ ((m & 7) << 4))]);
            acc = __builtin_amdgcn_mfma_f32_16x16x32_bf16(afr, bfrag, acc, 0, 0, 0);
        }
        // group fold on odd bodies
        if (half == 1) {
#pragma unroll
            for (int e = 0; e < 4; ++e) {
                unsigned oi = (unsigned)(gr0 + g * 16 + lg * 4 + e);
                float val = acc[e] * ahv[e];
                if (oi >= osw) psum1 += val; else psum0 += val;
            }
            acc = (f32x4){0.f, 0.f, 0.f, 0.f};
        }
    }

    // ---- epilogue ------------------------------------------------------------
    psum0 += __shfl_xor(psum0, 16); psum0 += __shfl_xor(psum0, 32);
    psum1 += __shfl_xor(psum1, 16); psum1 += __shfl_xor(psum1, 32);
    if (lane < 16) {
        Pblk[((size_t)b * 2 + 0) * 128 + m] = psum0;
        Pblk[((size_t)b * 2 + 1) * 128 + m] = psum1;
    }
#pragma unroll
    for (int off = 1; off < 64; off <<= 1) {
        sg0 += __shfl_xor(sg0, off); sg1 += __shfl_xor(sg1, off);
        sb0 += __shfl_xor(sb0, off); sb1 += __shfl_xor(sb1, off);
    }
    if (lane == 0) { redS[w] = sg0; redS[8 + w] = sg1; redS[16 + w] = sb0; redS[24 + w] = sb1; }
    __syncthreads();
    if (tid < 2) {
        float S = 0.f, T = 0.f;
#pragma unroll
        for (int k = 0; k < 8; ++k) { S += redS[tid * 8 + k]; T += redS[16 + tid * 8 + k]; }
        SgPart[b * 2 + tid] = S;
        SbPart[b * 2 + tid] = T;
    }
}

// ---------- finalize: col-512 peel + LN fold + bias + relu -------------------
__global__ void finalize_kernel(const float* __restrict__ Pblk, const float* __restrict__ SgPart,
                                const float* __restrict__ SbPart, const float* __restrict__ w5g,
                                const float* __restrict__ w5b, const float* __restrict__ ahT,
                                const float* __restrict__ vh512, const float* __restrict__ mu,
                                const float* __restrict__ rsig, const float* __restrict__ bias,
                                float* __restrict__ out) {
    __shared__ float wg[HP], wb[HP];
    int o = blockIdx.x, m = threadIdx.x;   // 128 threads
    for (int i = m; i < HP; i += 128) {
        wg[i] = w5g[(size_t)o * HP + i];
        wb[i] = w5b[(size_t)o * HP + i];
    }
    __syncthreads();
    float Pf = 0.f, Sgf = 0.f, Sbf = 0.f;
    for (int i = 0; i < HP; ++i) {
        float g = wg[i];
        Pf = fmaf(ahT[(size_t)i * 128 + m], g, Pf);
        Sgf += g; Sbf += wb[i];
    }
    int b0 = (o * HP) >> 7, b1 = (o * HP + 512) >> 7;
    float P = 0.f, Sg = 0.f, Sb = 0.f;
    for (int bb = b0; bb <= b1; ++bb) {
        unsigned of = ((unsigned)bb * 128u) / 513u;
        int sl = o - (int)of;
        if (sl < 0 || sl > 1) continue;
        P  += Pblk[((size_t)bb * 2 + sl) * 128 + m];
        Sg += SgPart[bb * 2 + sl];
        Sb += SbPart[bb * 2 + sl];
    }
    P += vh512[m] * Pf;
    Sg += Sgf;
    Sb += Sbf;
    float x = rsig[m] * (P - mu[m] * Sg) + Sb + bias[o];
    out[m * OD + o] = fmaxf(x, 0.f);
}

extern "C" void kernel_launch(void* const* d_in, const int* in_sizes, int n_in,
                              void* d_out, int out_size, void* d_ws, size_t ws_size,
                              hipStream_t stream) {
    const float* a     = (const float*)d_in[0];
    const float* v     = (const float*)d_in[1];
    const float* gamma = (const float*)d_in[2];
    const float* beta  = (const float*)d_in[3];
    const float* W     = (const float*)d_in[4];
    const float* bias  = (const float*)d_in[5];
    float* out = (float*)d_out;

    float* cur = (float*)d_ws;
    float* mu     = cur; cur += 128;
    float* rsig   = cur; cur += 128;
    float* SgPart = cur; cur += NBLK * 2;               // 2052
    float* SbPart = cur; cur += NBLK * 2;               // 2052
    float* Pblk   = cur; cur += (size_t)NBLK * 2 * 128; // 262656
    float* ahT    = cur; cur += (size_t)HP * 128;       // 65664
    float* vh512  = cur; cur += 128;
    float* w5g    = cur; cur += (size_t)NBLK * 128;     // 131328
    float* w5b    = cur; cur += (size_t)NBLK * 128;     // 131328
    unsigned short* gpb = (unsigned short*)cur;          // 513*512
    unsigned short* bpb = gpb + (size_t)HP * 512;
    unsigned short* vhT = bpb + (size_t)HP * 512;        // 128*512

    prep_all<<<HP + 128 + 1 + 257, 256, 0, stream>>>(a, v, gamma, beta, gpb, bpb, vhT, vh512, ahT);
    prep_w5<<<HP, 256, 0, stream>>>(W, gamma, beta, w5g, w5b);
    stats_kernel<<<128, 256, 0, stream>>>(a, v, mu, rsig);
    stage_fused<<<NBLK, 512, 0, stream>>>(W, gpb, bpb, vhT, ahT, Pblk, SgPart, SbPart);
    finalize_kernel<<<OD, 128, 0, stream>>>(Pblk, SgPart, SbPart, w5g, w5b, ahT, vh512,
                                            mu, rsig, bias, out);
}